// Round 13
// baseline (1625.513 us; speedup 1.0000x reference)
//
#include <hip/hip_runtime.h>
#include <hip/hip_bf16.h>
#include <stdint.h>

typedef unsigned short u16;
typedef __bf16 v8bf __attribute__((ext_vector_type(8)));
typedef float f32x4 __attribute__((ext_vector_type(4)));

#define BATCH 2
#define NSEQ  2048
#define DIM_  2048
#define QH    16
#define KVH   4
#define HD    128
#define KVDIM 512
#define QKVS  3072
#define MROWS (BATCH*NSEQ)

__device__ __forceinline__ u16 f2bf(float f) {
  uint32_t u = __builtin_bit_cast(uint32_t, f);
  u += 0x7FFFu + ((u >> 16) & 1u);
  return (u16)(u >> 16);
}
__device__ __forceinline__ uint32_t cvt_pk_bf16(float lo, float hi) {
  uint32_t r;
  asm("v_cvt_pk_bf16_f32 %0, %1, %2" : "=v"(r) : "v"(lo), "v"(hi));
  return r;
}
__device__ __forceinline__ void gload_lds16(const void* g, void* l) {
  __builtin_amdgcn_global_load_lds((const __attribute__((address_space(1))) void*)g,
                                   (__attribute__((address_space(3))) void*)l, 16, 0, 0);
}

// ---------------- fused init: conv_x + conv_w + rope table — unchanged r12 ----------------
__global__ void k_init(const float* __restrict__ q, const float* __restrict__ k,
                       const float* __restrict__ v,
                       const float* __restrict__ wq, const float* __restrict__ wk,
                       const float* __restrict__ wv, const float* __restrict__ wo,
                       u16* __restrict__ xq, u16* __restrict__ xk, u16* __restrict__ xv,
                       u16* __restrict__ oq, u16* __restrict__ ok,
                       u16* __restrict__ ov, u16* __restrict__ oo,
                       float2* __restrict__ tab) {
  int bid = blockIdx.x;
  if (bid < 24576) {
    int i = (bid * 256 + threadIdx.x) * 4;
    int r = i >> 23;
    int e = i & ((1 << 23) - 1);
    const float* in = (r == 0) ? q : (r == 1 ? k : v);
    u16* out = (r == 0) ? xq : (r == 1 ? xk : xv);
    float4 vv = *(const float4*)(in + e);
    ushort4 o;
    o.x = f2bf(vv.x); o.y = f2bf(vv.y); o.z = f2bf(vv.z); o.w = f2bf(vv.w);
    *(ushort4*)(out + e) = o;
  } else if (bid < 34816) {
    int i = ((bid - 24576) * 256 + threadIdx.x) * 4;
    const float* in; u16* out; int e;
    if (i < 4194304)      { in = wq; out = oq; e = i; }
    else if (i < 5242880) { in = wk; out = ok; e = i - 4194304; }
    else if (i < 6291456) { in = wv; out = ov; e = i - 5242880; }
    else                  { in = wo; out = oo; e = i - 6291456; }
    float4 vv = *(const float4*)(in + e);
    ushort4 o;
    o.x = f2bf(vv.x); o.y = f2bf(vv.y); o.z = f2bf(vv.z); o.w = f2bf(vv.w);
    *(ushort4*)(out + e) = o;
  } else {
    int idx = (bid - 34816) * 256 + threadIdx.x;
    if (idx < NSEQ * 64) {
      int i = idx & 63;
      float inv = powf(10000.0f, -(float)i / 64.0f);
      float ang = (float)(idx >> 6) * inv;
      tab[idx] = make_float2(cosf(ang), sinf(ang));
    }
  }
}

// ------- V transpose, LDS-tiled 64x64 — unchanged -------
__global__ __launch_bounds__(256) void k_transpose_v(const u16* __restrict__ vp, u16* __restrict__ vt) {
  __shared__ u16 t[64][72];
  int bn = blockIdx.x, bd = blockIdx.y;
  int tid = threadIdx.x;
  int rrow = tid >> 3;
  int rcol = (tid & 7) * 8;
#pragma unroll
  for (int i = 0; i < 2; ++i) {
    int n = rrow + i * 32;
    ushort4 v0 = *(const ushort4*)(vp + (size_t)(bn * 64 + n) * QKVS + bd * 64 + rcol);
    ushort4 v1 = *(const ushort4*)(vp + (size_t)(bn * 64 + n) * QKVS + bd * 64 + rcol + 4);
    *(ushort4*)&t[n][rcol] = v0;
    *(ushort4*)&t[n][rcol + 4] = v1;
  }
  __syncthreads();
  int b = bn >> 5;
  int nbase = (bn & 31) * 64;
#pragma unroll
  for (int i = 0; i < 2; ++i) {
    int dl = rrow + i * 32;
    int dglob = bd * 64 + dl;
    int kvh = dglob >> 7, dd = dglob & 127;
    ushort4 o0, o1;
    o0.x = t[rcol + 0][dl]; o0.y = t[rcol + 1][dl];
    o0.z = t[rcol + 2][dl]; o0.w = t[rcol + 3][dl];
    o1.x = t[rcol + 4][dl]; o1.y = t[rcol + 5][dl];
    o1.z = t[rcol + 6][dl]; o1.w = t[rcol + 7][dl];
    u16* dst = vt + (((size_t)(b * KVH + kvh) * HD + dd) * NSEQ + nbase + rcol);
    *(ushort4*)dst = o0;
    *(ushort4*)(dst + 4) = o1;
  }
}

// ---- fused QKV GEMM (2-phase dbuf) + RoPE — unchanged ----
__global__ __launch_bounds__(256) void k_gemm_qkv(const u16* __restrict__ xq, const u16* __restrict__ xk,
                                                  const u16* __restrict__ xv,
                                                  const u16* __restrict__ wq, const u16* __restrict__ wk,
                                                  const u16* __restrict__ wv,
                                                  const float* __restrict__ bq, const float* __restrict__ bk,
                                                  const float* __restrict__ bv,
                                                  const float2* __restrict__ tab2, u16* __restrict__ C) {
  __shared__ __align__(16) u16 As[2][128 * 32];
  __shared__ __align__(16) u16 Bs[2][128 * 32];
  int tid = threadIdx.x;
  int l = tid & 63, w = tid >> 6;
  int lg = l >> 4, lr = l & 15;
  int wr = w >> 1, wc = w & 1;
  int bm = blockIdx.x, bn = blockIdx.y;

  const u16* A; const u16* B; const float* bias;
  if (bn < 16)      { A = xq; B = wq + (size_t)(bn * 128) * 2048;        bias = bq + bn * 128; }
  else if (bn < 20) { A = xk; B = wk + (size_t)((bn - 16) * 128) * 2048; bias = bk + (bn - 16) * 128; }
  else              { A = xv; B = wv + (size_t)((bn - 20) * 128) * 2048; bias = bv + (bn - 20) * 128; }

  int srow = tid >> 2;
  int scol = (tid & 3) * 16;

  const char* Ab = (const char*)A + ((size_t)(bm * 128 + srow) * 2048) * 2 + scol;
  const char* Bb = (const char*)B + ((size_t)srow * 2048) * 2 + scol;

#define STG(BUF, KT)                                                            \
  {                                                                             \
    size_t koff = (size_t)(KT) * 64;                                            \
    gload_lds16(Ab + koff, (char*)As[BUF] + srow * 64 + scol);                  \
    gload_lds16(Ab + koff + (size_t)64 * 2048 * 2,                              \
                (char*)As[BUF] + (srow + 64) * 64 + scol);                      \
    gload_lds16(Bb + koff, (char*)Bs[BUF] + srow * 64 + scol);                  \
    gload_lds16(Bb + koff + (size_t)64 * 2048 * 2,                              \
                (char*)Bs[BUF] + (srow + 64) * 64 + scol);                      \
  }

  f32x4 acc[4][4] = {};
  STG(0, 0);
  __syncthreads();
  for (int kt = 0; kt < 64; ++kt) {
    int cur = kt & 1;
    if (kt < 63) STG(cur ^ 1, kt + 1);
    const char* AsB = (const char*)As[cur];
    const char* BsB = (const char*)Bs[cur];
    v8bf af[4], bfr[4];
#pragma unroll
    for (int mi = 0; mi < 4; ++mi)
      af[mi] = *(const v8bf*)(AsB + (wr * 64 + mi * 16 + lr) * 64 + lg * 16);
#pragma unroll
    for (int ni = 0; ni < 4; ++ni)
      bfr[ni] = *(const v8bf*)(BsB + (wc * 64 + ni * 16 + lr) * 64 + lg * 16);
#pragma unroll
    for (int mi = 0; mi < 4; ++mi)
#pragma unroll
      for (int ni = 0; ni < 4; ++ni)
        acc[mi][ni] = __builtin_amdgcn_mfma_f32_16x16x32_bf16(af[mi], bfr[ni], acc[mi][ni], 0, 0, 0);
    __syncthreads();
  }
#undef STG

  bool rope = (bn < 20);
#pragma unroll
  for (int mi = 0; mi < 4; ++mi)
#pragma unroll
    for (int ni = 0; ni < 4; ++ni) {
      int grow0 = bm * 128 + wr * 64 + mi * 16 + lg * 4;
      int lcol = wc * 64 + ni * 16 + lr;
      int gcol = bn * 128 + lcol;
      float bsv = bias[lcol];
      if (rope) {
        int i2 = (gcol & 127) >> 1;
#pragma unroll
        for (int r = 0; r < 4; ++r) {
          float v = acc[mi][ni][r] + bsv;
          float pv = __shfl_xor(v, 1);
          int t = (grow0 + r) & (NSEQ - 1);
          float2 cs = tab2[t * 64 + i2];
          float y = (lr & 1) ? (pv * cs.y + v * cs.x) : (v * cs.x - pv * cs.y);
          C[(size_t)(grow0 + r) * QKVS + gcol] = f2bf(y);
        }
      } else {
#pragma unroll
        for (int r = 0; r < 4; ++r)
          C[(size_t)(grow0 + r) * QKVS + gcol] = f2bf(acc[mi][ni][r] + bsv);
      }
    }
}

// ---------------- bf16 GEMM (2-phase dbuf): fp32 out — unchanged ----------------
__global__ __launch_bounds__(256) void k_gemm_bt(const u16* __restrict__ A, const u16* __restrict__ B,
                                                 const float* __restrict__ bias, float* __restrict__ C,
                                                 int M, int N, int K) {
  __shared__ __align__(16) u16 As[2][128 * 32];
  __shared__ __align__(16) u16 Bs[2][128 * 32];
  int tid = threadIdx.x;
  int l = tid & 63, w = tid >> 6;
  int lg = l >> 4, lr = l & 15;
  int wr = w >> 1, wc = w & 1;
  int bm = blockIdx.x, bn = blockIdx.y;

  int srow = tid >> 2;
  int scol = (tid & 3) * 16;

  const char* Ab = (const char*)A + ((size_t)(bm * 128 + srow) * K) * 2 + scol;
  const char* Bb = (const char*)B + ((size_t)(bn * 128 + srow) * K) * 2 + scol;

#define STG(BUF, KT)                                                            \
  {                                                                             \
    size_t koff = (size_t)(KT) * 64;                                            \
    gload_lds16(Ab + koff, (char*)As[BUF] + srow * 64 + scol);                  \
    gload_lds16(Ab + koff + (size_t)64 * K * 2,                                 \
                (char*)As[BUF] + (srow + 64) * 64 + scol);                      \
    gload_lds16(Bb + koff, (char*)Bs[BUF] + srow * 64 + scol);                  \
    gload_lds16(Bb + koff + (size_t)64 * K * 2,                                 \
                (char*)Bs[BUF] + (srow + 64) * 64 + scol);                      \
  }

  f32x4 acc[4][4] = {};
  int ksteps = K >> 5;
  STG(0, 0);
  __syncthreads();
  for (int kt = 0; kt < ksteps; ++kt) {
    int cur = kt & 1;
    if (kt + 1 < ksteps) STG(cur ^ 1, kt + 1);
    const char* AsB = (const char*)As[cur];
    const char* BsB = (const char*)Bs[cur];
    v8bf af[4], bfr[4];
#pragma unroll
    for (int mi = 0; mi < 4; ++mi)
      af[mi] = *(const v8bf*)(AsB + (wr * 64 + mi * 16 + lr) * 64 + lg * 16);
#pragma unroll
    for (int ni = 0; ni < 4; ++ni)
      bfr[ni] = *(const v8bf*)(BsB + (wc * 64 + ni * 16 + lr) * 64 + lg * 16);
#pragma unroll
    for (int mi = 0; mi < 4; ++mi)
#pragma unroll
      for (int ni = 0; ni < 4; ++ni)
        acc[mi][ni] = __builtin_amdgcn_mfma_f32_16x16x32_bf16(af[mi], bfr[ni], acc[mi][ni], 0, 0, 0);
    __syncthreads();
  }
#undef STG

#pragma unroll
  for (int mi = 0; mi < 4; ++mi)
#pragma unroll
    for (int ni = 0; ni < 4; ++ni) {
      int grow0 = bm * 128 + wr * 64 + mi * 16 + lg * 4;
      int gcol = bn * 128 + wc * 64 + ni * 16 + lr;
      float bsv = bias[gcol];
#pragma unroll
      for (int r = 0; r < 4; ++r)
        C[(size_t)(grow0 + r) * N + gcol] = acc[mi][ni][r] + bsv;
    }
}

// ---------------- flash attention v7: 32 q-rows/wave, shared kf/vf reads ----------------
// 4 waves x 32 q-rows = 128-row q-tile; KVBLK=64 dbuf; each kf/vf LDS read feeds 2 MFMA
// (q-groups g=0: rows w*16, g=1: rows 64+w*16). Complement dispatch map across batch
// rounds balances causal load (perf heuristic only).
__global__ __launch_bounds__(256, 2) void k_attn(const u16* __restrict__ q, const u16* __restrict__ k,
                                                 const u16* __restrict__ vt, u16* __restrict__ out) {
  __shared__ __align__(16) u16 Ks[2][64 * 128];   // rows=psi(kv), 256B rows, XOR-swizzled
  __shared__ __align__(16) u16 Vs[2][128 * 64];   // rows=d, 128B rows, XOR-swizzled

  int tid = threadIdx.x;
  int l = tid & 63, w = tid >> 6;              // w: 0..3
  int lg = l >> 4, lr = l & 15;
  int h = blockIdx.y, b = blockIdx.z;
  int kvh = h >> 2;
  const float SCL2 = 0.12752551286084109f;  // (1/sqrt(128)) * log2(e)
  const float THR2 = 11.541560327111708f;   // 8 * log2(e)

  // complement mapping: first dispatch round (b=0) qt=bx, second (b=1) qt=15-bx
  int qt = b ? (15 - blockIdx.x) : blockIdx.x;

  const char* kbase = (const char*)k + ((size_t)(b * NSEQ) * QKVS + kvh * HD) * 2;
  const char* vbase = (const char*)vt + ((size_t)(b * KVH + kvh) * HD) * NSEQ * 2;

  int krow0 = tid >> 4;
  int kcol = (tid & 15) * 16;
  int vrow0 = tid >> 3;
  int vcol = (tid & 7) * 16;

  v8bf kr[4], vr[4];

#define LOADKV(KT)                                                                          \
  {                                                                                         \
    _Pragma("unroll") for (int i = 0; i < 4; ++i)                                           \
        kr[i] = *(const v8bf*)(kbase + (size_t)((KT) * 64 + krow0 + i * 16) * QKVS * 2 + kcol); \
    _Pragma("unroll") for (int i = 0; i < 4; ++i)                                           \
        vr[i] = *(const v8bf*)(vbase + (size_t)(vrow0 + i * 32) * NSEQ * 2 + (size_t)(KT) * 128 + vcol); \
  }
#define WRITEKV(BUF)                                                                        \
  {                                                                                         \
    char* KsB_ = (char*)Ks[BUF];                                                            \
    char* VsB_ = (char*)Vs[BUF];                                                            \
    _Pragma("unroll") for (int i = 0; i < 4; ++i) {                                         \
      int kvl = krow0 + i * 16;                                                             \
      int prow = (kvl & 32) + ((kvl & 4) << 2) + ((kvl & 24) >> 1) + (kvl & 3);             \
      *(v8bf*)(KsB_ + prow * 256 + (kcol ^ ((prow & 7) << 4))) = kr[i];                     \
    }                                                                                       \
    _Pragma("unroll") for (int i = 0; i < 4; ++i) {                                         \
      int row = vrow0 + i * 32;                                                             \
      *(v8bf*)(VsB_ + row * 128 + (vcol ^ ((row & 7) << 4))) = vr[i];                       \
    }                                                                                       \
  }

  // q-rows: group g at qt*128 + g*64 + w*16
  int q00 = qt * 128 + w * 16;          // g=0
  int q01 = qt * 128 + 64 + w * 16;     // g=1

  v8bf qf0[4], qf1[4];
  {
    const char* qb0 = (const char*)q + ((size_t)(b * NSEQ + q00 + lr) * QKVS + h * HD) * 2;
    const char* qb1 = (const char*)q + ((size_t)(b * NSEQ + q01 + lr) * QKVS + h * HD) * 2;
#pragma unroll
    for (int kk = 0; kk < 4; ++kk) {
      qf0[kk] = *(const v8bf*)(qb0 + kk * 64 + lg * 16);
      qf1[kk] = *(const v8bf*)(qb1 + kk * 64 + lg * 16);
    }
  }

  f32x4 od0[8] = {}, od1[8] = {};
  float m20 = -INFINITY, lsum0 = 0.f;
  float m21 = -INFINITY, lsum1 = 0.f;
  int qrow0 = q00 + lr, qrow1 = q01 + lr;

  int ktmax0 = 2 * qt;       // g=0's last kv-tile (diagonal)
  int ktmax = 2 * qt + 1;    // g=1's last kv-tile (block loop bound)

  LOADKV(0);
  WRITEKV(0);
  __syncthreads();

  for (int kt = 0; kt <= ktmax; ++kt) {
    int cur = kt & 1;
    if (kt < ktmax) LOADKV(kt + 1);
    const char* KsB = (const char*)Ks[cur];
    const char* VsB = (const char*)Vs[cur];
    bool do0 = (kt <= ktmax0);

    // S^T = K Q^T (raw); kf read once, feeds both q-groups
    f32x4 st0[4], st1[4];
    __builtin_amdgcn_s_setprio(1);
#pragma unroll
    for (int nt = 0; nt < 4; ++nt) {
      f32x4 a0 = {}, a1 = {};
#pragma unroll
      for (int kk = 0; kk < 4; ++kk) {
        int krow = nt * 16 + lr;
        v8bf kf = *(const v8bf*)(KsB + krow * 256 + ((kk * 64 + lg * 16) ^ ((krow & 7) << 4)));
        a0 = __builtin_amdgcn_mfma_f32_16x16x32_bf16(kf, qf0[kk], a0, 0, 0, 0);
        a1 = __builtin_amdgcn_mfma_f32_16x16x32_bf16(kf, qf1[kk], a1, 0, 0, 0);
      }
      st0[nt] = a0; st1[nt] = a1;
    }
    __builtin_amdgcn_s_setprio(0);

    // ---- g=0 softmax (skip entirely past its diagonal) ----
    uint32_t pk0[4][2];
    if (do0) {
      if (kt == ktmax0) {
#pragma unroll
        for (int nt = 0; nt < 4; ++nt)
#pragma unroll
          for (int r = 0; r < 4; ++r) {
            int kv = kt * 64 + (nt >> 1) * 32 + lg * 8 + ((nt & 1) << 2) + r;
            if (kv > qrow0) st0[nt][r] = -1e30f;
          }
      }
      float mx = -1e30f;
#pragma unroll
      for (int nt = 0; nt < 4; ++nt)
#pragma unroll
        for (int r = 0; r < 4; ++r) mx = fmaxf(mx, st0[nt][r]);
      mx = fmaxf(mx, __shfl_xor(mx, 16));
      mx = fmaxf(mx, __shfl_xor(mx, 32));
      float mx2 = mx * SCL2;
      if (!__all(mx2 - m20 <= THR2)) {
        float nm2 = fmaxf(m20, mx2);
        float corrf = exp2f(m20 - nm2);
        m20 = nm2; lsum0 *= corrf;
#pragma unroll
        for (int r = 0; r < 4; ++r) {
          float cb = __shfl(corrf, lg * 4 + r);
#pragma unroll
          for (int dt = 0; dt < 8; ++dt) od0[dt][r] *= cb;
        }
      }
      float rs = 0.f;
#pragma unroll
      for (int nt = 0; nt < 4; ++nt)
#pragma unroll
        for (int r = 0; r < 4; ++r) {
          float pv = exp2f(fmaf(st0[nt][r], SCL2, -m20));
          st0[nt][r] = pv;
          rs += pv;
        }
      rs += __shfl_xor(rs, 16);
      rs += __shfl_xor(rs, 32);
      lsum0 += rs;
#pragma unroll
      for (int nt = 0; nt < 4; ++nt)
#pragma unroll
        for (int s = 0; s < 2; ++s)
          pk0[nt][s] = cvt_pk_bf16(st0[nt][2 * s], st0[nt][2 * s + 1]);
    }

    // ---- g=1 softmax ----
    uint32_t pk1[4][2];
    {
      if (kt == ktmax) {
#pragma unroll
        for (int nt = 0; nt < 4; ++nt)
#pragma unroll
          for (int r = 0; r < 4; ++r) {
            int kv = kt * 64 + (nt >> 1) * 32 + lg * 8 + ((nt & 1) << 2) + r;
            if (kv > qrow1) st1[nt][r] = -1e30f;
          }
      }
      float mx = -1e30f;
#pragma unroll
      for (int nt = 0; nt < 4; ++nt)
#pragma unroll
        for (int r = 0; r < 4; ++r) mx = fmaxf(mx, st1[nt][r]);
      mx = fmaxf(mx, __shfl_xor(mx, 16));
      mx = fmaxf(mx, __shfl_xor(mx, 32));
      float mx2 = mx * SCL2;
      if (!__all(mx2 - m21 <= THR2)) {
        float nm2 = fmaxf(m21, mx2);
        float corrf = exp2f(m21 - nm2);
        m21 = nm2; lsum1 *= corrf;
#pragma unroll
        for (int r = 0; r < 4; ++r) {
          float cb = __shfl(corrf, lg * 4 + r);
#pragma unroll
          for (int dt = 0; dt < 8; ++dt) od1[dt][r] *= cb;
        }
      }
      float rs = 0.f;
#pragma unroll
      for (int nt = 0; nt < 4; ++nt)
#pragma unroll
        for (int r = 0; r < 4; ++r) {
          float pv = exp2f(fmaf(st1[nt][r], SCL2, -m21));
          st1[nt][r] = pv;
          rs += pv;
        }
      rs += __shfl_xor(rs, 16);
      rs += __shfl_xor(rs, 32);
      lsum1 += rs;
#pragma unroll
      for (int nt = 0; nt < 4; ++nt)
#pragma unroll
        for (int s = 0; s < 2; ++s)
          pk1[nt][s] = cvt_pk_bf16(st1[nt][2 * s], st1[nt][2 * s + 1]);
    }

    // O += P V ; vf read once, feeds both groups
    __builtin_amdgcn_s_setprio(1);
#pragma unroll
    for (int kc = 0; kc < 2; ++kc) {
      union { uint32_t u[4]; v8bf v; } pf0, pf1;
      pf0.u[0] = pk0[2 * kc][0]; pf0.u[1] = pk0[2 * kc][1];
      pf0.u[2] = pk0[2 * kc + 1][0]; pf0.u[3] = pk0[2 * kc + 1][1];
      pf1.u[0] = pk1[2 * kc][0]; pf1.u[1] = pk1[2 * kc][1];
      pf1.u[2] = pk1[2 * kc + 1][0]; pf1.u[3] = pk1[2 * kc + 1][1];
#pragma unroll
      for (int dt = 0; dt < 8; ++dt) {
        int vrow = dt * 16 + lr;
        v8bf vf = *(const v8bf*)(VsB + vrow * 128 + ((kc * 64 + lg * 16) ^ ((vrow & 7) << 4)));
        if (do0) od0[dt] = __builtin_amdgcn_mfma_f32_16x16x32_bf16(pf0.v, vf, od0[dt], 0, 0, 0);
        od1[dt] = __builtin_amdgcn_mfma_f32_16x16x32_bf16(pf1.v, vf, od1[dt], 0, 0, 0);
      }
    }
    __builtin_amdgcn_s_setprio(0);

    if (kt < ktmax) WRITEKV(cur ^ 1);
    __syncthreads();
  }

  // normalize + write
#pragma unroll
  for (int r = 0; r < 4; ++r) {
    float ls0 = __shfl(lsum0, lg * 4 + r);
    float ls1 = __shfl(lsum1, lg * 4 + r);
    float inv0 = 1.0f / ls0;
    float inv1 = 1.0f / ls1;
    int qr0 = q00 + lg * 4 + r;
    int qr1 = q01 + lg * 4 + r;
    char* ob0 = (char*)out + ((size_t)(b * NSEQ + qr0) * DIM_ + h * HD) * 2;
    char* ob1 = (char*)out + ((size_t)(b * NSEQ + qr1) * DIM_ + h * HD) * 2;
#pragma unroll
    for (int dt = 0; dt < 8; ++dt) {
      *(u16*)(ob0 + (dt * 16 + lr) * 2) = f2bf(od0[dt][r] * inv0);
      *(u16*)(ob1 + (dt * 16 + lr) * 2) = f2bf(od1[dt][r] * inv1);
    }
  }
#undef LOADKV
#undef WRITEKV
}

// ---------------- launch ----------------
extern "C" void kernel_launch(void* const* d_in, const int* in_sizes, int n_in,
                              void* d_out, int out_size, void* d_ws, size_t ws_size,
                              hipStream_t stream) {
  const float* query = (const float*)d_in[0];
  const float* key_ = (const float*)d_in[1];
  const float* value = (const float*)d_in[2];
  const float* Wq = (const float*)d_in[3];
  const float* bq = (const float*)d_in[4];
  const float* Wk = (const float*)d_in[5];
  const float* bk = (const float*)d_in[6];
  const float* Wv = (const float*)d_in[7];
  const float* bv = (const float*)d_in[8];
  const float* Wo = (const float*)d_in[9];
  const float* bo = (const float*)d_in[10];

  char* ws = (char*)d_ws;
  u16* wq_bf = (u16*)(ws + 0);
  u16* wk_bf = (u16*)(ws + 8388608);
  u16* wv_bf = (u16*)(ws + 10485760);
  u16* wo_bf = (u16*)(ws + 12582912);
  float2* tab2 = (float2*)(ws + 20971520);
  u16* xq = (u16*)(ws + 22020096);
  u16* xk = (u16*)(ws + 38797312);
  u16* xv = (u16*)(ws + 55574528);
  u16* qkvproj = (u16*)(ws + 72351744);
  u16* vt = xq;       // xq dead after fused QKV GEMM
  u16* attno = xk;    // xk dead after fused QKV GEMM

  k_init<<<dim3(35328), 256, 0, stream>>>(query, key_, value, Wq, Wk, Wv, Wo,
                                          xq, xk, xv, wq_bf, wk_bf, wv_bf, wo_bf, tab2);

  k_gemm_qkv<<<dim3(MROWS / 128, QKVS / 128), 256, 0, stream>>>(xq, xk, xv, wq_bf, wk_bf, wv_bf,
                                                                bq, bk, bv, tab2, qkvproj);

  k_transpose_v<<<dim3(MROWS / 64, KVDIM / 64), 256, 0, stream>>>(qkvproj + 2560, vt);

  k_attn<<<dim3(NSEQ / 128, QH, BATCH), 256, 0, stream>>>(qkvproj, qkvproj + 2048, vt, attno);

  k_gemm_bt<<<dim3(MROWS / 128, DIM_ / 128), 256, 0, stream>>>(attno, wo_bf, bo, (float*)d_out, MROWS, DIM_, DIM_);
}

// Round 14
// 233.194 us; speedup vs baseline: 6.9706x; 6.9706x over previous
//
#include <hip/hip_runtime.h>
#include <hip/hip_bf16.h>
#include <stdint.h>

typedef unsigned short u16;
typedef __bf16 v8bf __attribute__((ext_vector_type(8)));
typedef float f32x4 __attribute__((ext_vector_type(4)));

#define BATCH 2
#define NSEQ  2048
#define DIM_  2048
#define QH    16
#define KVH   4
#define HD    128
#define KVDIM 512
#define QKVS  3072
#define MROWS (BATCH*NSEQ)

__device__ __forceinline__ u16 f2bf(float f) {
  uint32_t u = __builtin_bit_cast(uint32_t, f);
  u += 0x7FFFu + ((u >> 16) & 1u);
  return (u16)(u >> 16);
}
__device__ __forceinline__ uint32_t cvt_pk_bf16(float lo, float hi) {
  uint32_t r;
  asm("v_cvt_pk_bf16_f32 %0, %1, %2" : "=v"(r) : "v"(lo), "v"(hi));
  return r;
}
__device__ __forceinline__ void gload_lds16(const void* g, void* l) {
  __builtin_amdgcn_global_load_lds((const __attribute__((address_space(1))) void*)g,
                                   (__attribute__((address_space(3))) void*)l, 16, 0, 0);
}

// ---------------- fused init: conv_x + conv_w + rope table — unchanged r12 ----------------
__global__ void k_init(const float* __restrict__ q, const float* __restrict__ k,
                       const float* __restrict__ v,
                       const float* __restrict__ wq, const float* __restrict__ wk,
                       const float* __restrict__ wv, const float* __restrict__ wo,
                       u16* __restrict__ xq, u16* __restrict__ xk, u16* __restrict__ xv,
                       u16* __restrict__ oq, u16* __restrict__ ok,
                       u16* __restrict__ ov, u16* __restrict__ oo,
                       float2* __restrict__ tab) {
  int bid = blockIdx.x;
  if (bid < 24576) {
    int i = (bid * 256 + threadIdx.x) * 4;
    int r = i >> 23;
    int e = i & ((1 << 23) - 1);
    const float* in = (r == 0) ? q : (r == 1 ? k : v);
    u16* out = (r == 0) ? xq : (r == 1 ? xk : xv);
    float4 vv = *(const float4*)(in + e);
    ushort4 o;
    o.x = f2bf(vv.x); o.y = f2bf(vv.y); o.z = f2bf(vv.z); o.w = f2bf(vv.w);
    *(ushort4*)(out + e) = o;
  } else if (bid < 34816) {
    int i = ((bid - 24576) * 256 + threadIdx.x) * 4;
    const float* in; u16* out; int e;
    if (i < 4194304)      { in = wq; out = oq; e = i; }
    else if (i < 5242880) { in = wk; out = ok; e = i - 4194304; }
    else if (i < 6291456) { in = wv; out = ov; e = i - 5242880; }
    else                  { in = wo; out = oo; e = i - 6291456; }
    float4 vv = *(const float4*)(in + e);
    ushort4 o;
    o.x = f2bf(vv.x); o.y = f2bf(vv.y); o.z = f2bf(vv.z); o.w = f2bf(vv.w);
    *(ushort4*)(out + e) = o;
  } else {
    int idx = (bid - 34816) * 256 + threadIdx.x;
    if (idx < NSEQ * 64) {
      int i = idx & 63;
      float inv = powf(10000.0f, -(float)i / 64.0f);
      float ang = (float)(idx >> 6) * inv;
      tab[idx] = make_float2(cosf(ang), sinf(ang));
    }
  }
}

// ------- V transpose, LDS-tiled 64x64 — unchanged -------
__global__ __launch_bounds__(256) void k_transpose_v(const u16* __restrict__ vp, u16* __restrict__ vt) {
  __shared__ u16 t[64][72];
  int bn = blockIdx.x, bd = blockIdx.y;
  int tid = threadIdx.x;
  int rrow = tid >> 3;
  int rcol = (tid & 7) * 8;
#pragma unroll
  for (int i = 0; i < 2; ++i) {
    int n = rrow + i * 32;
    ushort4 v0 = *(const ushort4*)(vp + (size_t)(bn * 64 + n) * QKVS + bd * 64 + rcol);
    ushort4 v1 = *(const ushort4*)(vp + (size_t)(bn * 64 + n) * QKVS + bd * 64 + rcol + 4);
    *(ushort4*)&t[n][rcol] = v0;
    *(ushort4*)&t[n][rcol + 4] = v1;
  }
  __syncthreads();
  int b = bn >> 5;
  int nbase = (bn & 31) * 64;
#pragma unroll
  for (int i = 0; i < 2; ++i) {
    int dl = rrow + i * 32;
    int dglob = bd * 64 + dl;
    int kvh = dglob >> 7, dd = dglob & 127;
    ushort4 o0, o1;
    o0.x = t[rcol + 0][dl]; o0.y = t[rcol + 1][dl];
    o0.z = t[rcol + 2][dl]; o0.w = t[rcol + 3][dl];
    o1.x = t[rcol + 4][dl]; o1.y = t[rcol + 5][dl];
    o1.z = t[rcol + 6][dl]; o1.w = t[rcol + 7][dl];
    u16* dst = vt + (((size_t)(b * KVH + kvh) * HD + dd) * NSEQ + nbase + rcol);
    *(ushort4*)dst = o0;
    *(ushort4*)(dst + 4) = o1;
  }
}

// ---- fused QKV GEMM: 3-buffer LDS, raw barrier + counted vmcnt(8), RoPE epilogue ----
// Safety: STG at step kt writes buf (kt+2)%3 (last read at kt-1, retired before this
// step's barrier); reads at kt need STG(kt-2) -> only STG(kt-1)'s 8 loads are newer
// -> vmcnt(8); final step: predecessor issued nothing -> vmcnt(0).
__global__ __launch_bounds__(256) void k_gemm_qkv(const u16* __restrict__ xq, const u16* __restrict__ xk,
                                                  const u16* __restrict__ xv,
                                                  const u16* __restrict__ wq, const u16* __restrict__ wk,
                                                  const u16* __restrict__ wv,
                                                  const float* __restrict__ bq, const float* __restrict__ bk,
                                                  const float* __restrict__ bv,
                                                  const float2* __restrict__ tab2, u16* __restrict__ C) {
  __shared__ __align__(16) u16 As[3][128 * 32];
  __shared__ __align__(16) u16 Bs[3][128 * 32];
  int tid = threadIdx.x;
  int l = tid & 63, w = tid >> 6;
  int lg = l >> 4, lr = l & 15;
  int wr = w >> 1, wc = w & 1;
  int bm = blockIdx.x, bn = blockIdx.y;

  const u16* A; const u16* B; const float* bias;
  if (bn < 16)      { A = xq; B = wq + (size_t)(bn * 128) * 2048;        bias = bq + bn * 128; }
  else if (bn < 20) { A = xk; B = wk + (size_t)((bn - 16) * 128) * 2048; bias = bk + (bn - 16) * 128; }
  else              { A = xv; B = wv + (size_t)((bn - 20) * 128) * 2048; bias = bv + (bn - 20) * 128; }

  int srow = tid >> 2;
  int scol = (tid & 3) * 16;

  const char* Ab = (const char*)A + ((size_t)(bm * 128 + srow) * 2048) * 2 + scol;
  const char* Bb = (const char*)B + ((size_t)srow * 2048) * 2 + scol;

#define STG(BUF, KT)                                                            \
  {                                                                             \
    size_t koff = (size_t)(KT) * 64;                                            \
    gload_lds16(Ab + koff, (char*)As[BUF] + srow * 64 + scol);                  \
    gload_lds16(Ab + koff + (size_t)64 * 2048 * 2,                              \
                (char*)As[BUF] + (srow + 64) * 64 + scol);                      \
    gload_lds16(Bb + koff, (char*)Bs[BUF] + srow * 64 + scol);                  \
    gload_lds16(Bb + koff + (size_t)64 * 2048 * 2,                              \
                (char*)Bs[BUF] + (srow + 64) * 64 + scol);                      \
  }

  f32x4 acc[4][4] = {};
  STG(0, 0);
  STG(1, 1);
  for (int kt = 0; kt < 64; ++kt) {
    if (kt == 63) { asm volatile("s_waitcnt vmcnt(0)" ::: "memory"); }
    else          { asm volatile("s_waitcnt vmcnt(8)" ::: "memory"); }
    __builtin_amdgcn_s_barrier();
    if (kt < 62) STG((kt + 2) % 3, kt + 2);
    const char* AsB = (const char*)As[kt % 3];
    const char* BsB = (const char*)Bs[kt % 3];
    v8bf af[4], bfr[4];
#pragma unroll
    for (int mi = 0; mi < 4; ++mi)
      af[mi] = *(const v8bf*)(AsB + (wr * 64 + mi * 16 + lr) * 64 + lg * 16);
#pragma unroll
    for (int ni = 0; ni < 4; ++ni)
      bfr[ni] = *(const v8bf*)(BsB + (wc * 64 + ni * 16 + lr) * 64 + lg * 16);
#pragma unroll
    for (int mi = 0; mi < 4; ++mi)
#pragma unroll
      for (int ni = 0; ni < 4; ++ni)
        acc[mi][ni] = __builtin_amdgcn_mfma_f32_16x16x32_bf16(af[mi], bfr[ni], acc[mi][ni], 0, 0, 0);
  }
#undef STG

  bool rope = (bn < 20);
#pragma unroll
  for (int mi = 0; mi < 4; ++mi)
#pragma unroll
    for (int ni = 0; ni < 4; ++ni) {
      int grow0 = bm * 128 + wr * 64 + mi * 16 + lg * 4;
      int lcol = wc * 64 + ni * 16 + lr;
      int gcol = bn * 128 + lcol;
      float bsv = bias[lcol];
      if (rope) {
        int i2 = (gcol & 127) >> 1;
#pragma unroll
        for (int r = 0; r < 4; ++r) {
          float v = acc[mi][ni][r] + bsv;
          float pv = __shfl_xor(v, 1);
          int t = (grow0 + r) & (NSEQ - 1);
          float2 cs = tab2[t * 64 + i2];
          float y = (lr & 1) ? (pv * cs.y + v * cs.x) : (v * cs.x - pv * cs.y);
          C[(size_t)(grow0 + r) * QKVS + gcol] = f2bf(y);
        }
      } else {
#pragma unroll
        for (int r = 0; r < 4; ++r)
          C[(size_t)(grow0 + r) * QKVS + gcol] = f2bf(acc[mi][ni][r] + bsv);
      }
    }
}

// ---------------- bf16 GEMM: 3-buffer counted-vmcnt, fp32 out ----------------
__global__ __launch_bounds__(256) void k_gemm_bt(const u16* __restrict__ A, const u16* __restrict__ B,
                                                 const float* __restrict__ bias, float* __restrict__ C,
                                                 int M, int N, int K) {
  __shared__ __align__(16) u16 As[3][128 * 32];
  __shared__ __align__(16) u16 Bs[3][128 * 32];
  int tid = threadIdx.x;
  int l = tid & 63, w = tid >> 6;
  int lg = l >> 4, lr = l & 15;
  int wr = w >> 1, wc = w & 1;
  int bm = blockIdx.x, bn = blockIdx.y;

  int srow = tid >> 2;
  int scol = (tid & 3) * 16;

  const char* Ab = (const char*)A + ((size_t)(bm * 128 + srow) * K) * 2 + scol;
  const char* Bb = (const char*)B + ((size_t)(bn * 128 + srow) * K) * 2 + scol;

#define STG(BUF, KT)                                                            \
  {                                                                             \
    size_t koff = (size_t)(KT) * 64;                                            \
    gload_lds16(Ab + koff, (char*)As[BUF] + srow * 64 + scol);                  \
    gload_lds16(Ab + koff + (size_t)64 * K * 2,                                 \
                (char*)As[BUF] + (srow + 64) * 64 + scol);                      \
    gload_lds16(Bb + koff, (char*)Bs[BUF] + srow * 64 + scol);                  \
    gload_lds16(Bb + koff + (size_t)64 * K * 2,                                 \
                (char*)Bs[BUF] + (srow + 64) * 64 + scol);                      \
  }

  f32x4 acc[4][4] = {};
  int ksteps = K >> 5;
  STG(0, 0);
  STG(1, 1);
  for (int kt = 0; kt < ksteps; ++kt) {
    if (kt == ksteps - 1) { asm volatile("s_waitcnt vmcnt(0)" ::: "memory"); }
    else                  { asm volatile("s_waitcnt vmcnt(8)" ::: "memory"); }
    __builtin_amdgcn_s_barrier();
    if (kt + 2 < ksteps) STG((kt + 2) % 3, kt + 2);
    const char* AsB = (const char*)As[kt % 3];
    const char* BsB = (const char*)Bs[kt % 3];
    v8bf af[4], bfr[4];
#pragma unroll
    for (int mi = 0; mi < 4; ++mi)
      af[mi] = *(const v8bf*)(AsB + (wr * 64 + mi * 16 + lr) * 64 + lg * 16);
#pragma unroll
    for (int ni = 0; ni < 4; ++ni)
      bfr[ni] = *(const v8bf*)(BsB + (wc * 64 + ni * 16 + lr) * 64 + lg * 16);
#pragma unroll
    for (int mi = 0; mi < 4; ++mi)
#pragma unroll
      for (int ni = 0; ni < 4; ++ni)
        acc[mi][ni] = __builtin_amdgcn_mfma_f32_16x16x32_bf16(af[mi], bfr[ni], acc[mi][ni], 0, 0, 0);
  }
#undef STG

#pragma unroll
  for (int mi = 0; mi < 4; ++mi)
#pragma unroll
    for (int ni = 0; ni < 4; ++ni) {
      int grow0 = bm * 128 + wr * 64 + mi * 16 + lg * 4;
      int gcol = bn * 128 + wc * 64 + ni * 16 + lr;
      float bsv = bias[gcol];
#pragma unroll
      for (int r = 0; r < 4; ++r)
        C[(size_t)(grow0 + r) * N + gcol] = acc[mi][ni][r] + bsv;
    }
}

// ---------------- flash attention v6 (r12-verified): dbuf K/V, 1 barrier/iter ----------------
__global__ __launch_bounds__(256, 2) void k_attn(const u16* __restrict__ q, const u16* __restrict__ k,
                                                 const u16* __restrict__ vt, u16* __restrict__ out) {
  __shared__ __align__(16) u16 Ks[2][64 * 128];
  __shared__ __align__(16) u16 Vs[2][128 * 64];

  int tid = threadIdx.x;
  int l = tid & 63, w = tid >> 6;
  int lg = l >> 4, lr = l & 15;
  int h = blockIdx.y, b = blockIdx.z;
  int kvh = h >> 2;
  const float SCL2 = 0.12752551286084109f;
  const float THR2 = 11.541560327111708f;

  const char* kbase = (const char*)k + ((size_t)(b * NSEQ) * QKVS + kvh * HD) * 2;
  const char* vbase = (const char*)vt + ((size_t)(b * KVH + kvh) * HD) * NSEQ * 2;

  int krow0 = tid >> 4;
  int kcol = (tid & 15) * 16;
  int vrow0 = tid >> 3;
  int vcol = (tid & 7) * 16;

  v8bf kr[4], vr[4];

#define LOADKV(KT)                                                                          \
  {                                                                                         \
    _Pragma("unroll") for (int i = 0; i < 4; ++i)                                           \
        kr[i] = *(const v8bf*)(kbase + (size_t)((KT) * 64 + krow0 + i * 16) * QKVS * 2 + kcol); \
    _Pragma("unroll") for (int i = 0; i < 4; ++i)                                           \
        vr[i] = *(const v8bf*)(vbase + (size_t)(vrow0 + i * 32) * NSEQ * 2 + (size_t)(KT) * 128 + vcol); \
  }
#define WRITEKV(BUF)                                                                        \
  {                                                                                         \
    char* KsB_ = (char*)Ks[BUF];                                                            \
    char* VsB_ = (char*)Vs[BUF];                                                            \
    _Pragma("unroll") for (int i = 0; i < 4; ++i) {                                         \
      int kvl = krow0 + i * 16;                                                             \
      int prow = (kvl & 32) + ((kvl & 4) << 2) + ((kvl & 24) >> 1) + (kvl & 3);             \
      *(v8bf*)(KsB_ + prow * 256 + (kcol ^ ((prow & 7) << 4))) = kr[i];                     \
    }                                                                                       \
    _Pragma("unroll") for (int i = 0; i < 4; ++i) {                                         \
      int row = vrow0 + i * 32;                                                             \
      *(v8bf*)(VsB_ + row * 128 + (vcol ^ ((row & 7) << 4))) = vr[i];                       \
    }                                                                                       \
  }

  for (int pass = 0; pass < 2; ++pass) {
    int qt = pass ? (31 - blockIdx.x) : blockIdx.x;
    int q0 = qt * 64 + w * 16;

    const char* qb = (const char*)q + ((size_t)(b * NSEQ + q0 + lr) * QKVS + h * HD) * 2;
    v8bf qf[4];
#pragma unroll
    for (int kk = 0; kk < 4; ++kk) qf[kk] = *(const v8bf*)(qb + kk * 64 + lg * 16);

    f32x4 od[8] = {};
    float m2 = -INFINITY, lsum = 0.f;
    int qrow = q0 + lr;

    int ktmax = qt;
    LOADKV(0);
    WRITEKV(0);
    __syncthreads();

    for (int kt = 0; kt <= ktmax; ++kt) {
      int cur = kt & 1;
      if (kt < ktmax) LOADKV(kt + 1);
      const char* KsB = (const char*)Ks[cur];
      const char* VsB = (const char*)Vs[cur];

      f32x4 st[4];
      __builtin_amdgcn_s_setprio(1);
#pragma unroll
      for (int nt = 0; nt < 4; ++nt) {
        f32x4 a = {};
#pragma unroll
        for (int kk = 0; kk < 4; ++kk) {
          int krow = nt * 16 + lr;
          v8bf kf = *(const v8bf*)(KsB + krow * 256 + ((kk * 64 + lg * 16) ^ ((krow & 7) << 4)));
          a = __builtin_amdgcn_mfma_f32_16x16x32_bf16(kf, qf[kk], a, 0, 0, 0);
        }
        st[nt] = a;
      }
      __builtin_amdgcn_s_setprio(0);

      if (kt == ktmax) {
#pragma unroll
        for (int nt = 0; nt < 4; ++nt)
#pragma unroll
          for (int r = 0; r < 4; ++r) {
            int kv = kt * 64 + (nt >> 1) * 32 + lg * 8 + ((nt & 1) << 2) + r;
            if (kv > qrow) st[nt][r] = -1e30f;
          }
      }

      float mx = -1e30f;
#pragma unroll
      for (int nt = 0; nt < 4; ++nt)
#pragma unroll
        for (int r = 0; r < 4; ++r) mx = fmaxf(mx, st[nt][r]);
      mx = fmaxf(mx, __shfl_xor(mx, 16));
      mx = fmaxf(mx, __shfl_xor(mx, 32));
      float mx2 = mx * SCL2;

      if (!__all(mx2 - m2 <= THR2)) {
        float nm2 = fmaxf(m2, mx2);
        float corrf = exp2f(m2 - nm2);
        m2 = nm2;
        lsum *= corrf;
#pragma unroll
        for (int r = 0; r < 4; ++r) {
          float cb = __shfl(corrf, lg * 4 + r);
#pragma unroll
          for (int dt = 0; dt < 8; ++dt) od[dt][r] *= cb;
        }
      }

      float rs = 0.f;
#pragma unroll
      for (int nt = 0; nt < 4; ++nt)
#pragma unroll
        for (int r = 0; r < 4; ++r) {
          float pv = exp2f(fmaf(st[nt][r], SCL2, -m2));
          st[nt][r] = pv;
          rs += pv;
        }
      rs += __shfl_xor(rs, 16);
      rs += __shfl_xor(rs, 32);
      lsum += rs;

      uint32_t pk[4][2];
#pragma unroll
      for (int nt = 0; nt < 4; ++nt)
#pragma unroll
        for (int s = 0; s < 2; ++s)
          pk[nt][s] = cvt_pk_bf16(st[nt][2 * s], st[nt][2 * s + 1]);

      __builtin_amdgcn_s_setprio(1);
#pragma unroll
      for (int kc = 0; kc < 2; ++kc) {
        union { uint32_t u[4]; v8bf v; } pfu;
        pfu.u[0] = pk[2 * kc][0];
        pfu.u[1] = pk[2 * kc][1];
        pfu.u[2] = pk[2 * kc + 1][0];
        pfu.u[3] = pk[2 * kc + 1][1];
#pragma unroll
        for (int dt = 0; dt < 8; ++dt) {
          int vrow = dt * 16 + lr;
          v8bf vf = *(const v8bf*)(VsB + vrow * 128 + ((kc * 64 + lg * 16) ^ ((vrow & 7) << 4)));
          od[dt] = __builtin_amdgcn_mfma_f32_16x16x32_bf16(pfu.v, vf, od[dt], 0, 0, 0);
        }
      }
      __builtin_amdgcn_s_setprio(0);

      if (kt < ktmax) WRITEKV(cur ^ 1);
      __syncthreads();
    }

#pragma unroll
    for (int r = 0; r < 4; ++r) {
      float ls = __shfl(lsum, lg * 4 + r);
      float inv = 1.0f / ls;
      int qr = q0 + lg * 4 + r;
      char* ob = (char*)out + ((size_t)(b * NSEQ + qr) * DIM_ + h * HD) * 2;
#pragma unroll
      for (int dt = 0; dt < 8; ++dt)
        *(u16*)(ob + (dt * 16 + lr) * 2) = f2bf(od[dt][r] * inv);
    }
  }
#undef LOADKV
#undef WRITEKV
}

// ---------------- launch ----------------
extern "C" void kernel_launch(void* const* d_in, const int* in_sizes, int n_in,
                              void* d_out, int out_size, void* d_ws, size_t ws_size,
                              hipStream_t stream) {
  const float* query = (const float*)d_in[0];
  const float* key_ = (const float*)d_in[1];
  const float* value = (const float*)d_in[2];
  const float* Wq = (const float*)d_in[3];
  const float* bq = (const float*)d_in[4];
  const float* Wk = (const float*)d_in[5];
  const float* bk = (const float*)d_in[6];
  const float* Wv = (const float*)d_in[7];
  const float* bv = (const float*)d_in[8];
  const float* Wo = (const float*)d_in[9];
  const float* bo = (const float*)d_in[10];

  char* ws = (char*)d_ws;
  u16* wq_bf = (u16*)(ws + 0);
  u16* wk_bf = (u16*)(ws + 8388608);
  u16* wv_bf = (u16*)(ws + 10485760);
  u16* wo_bf = (u16*)(ws + 12582912);
  float2* tab2 = (float2*)(ws + 20971520);
  u16* xq = (u16*)(ws + 22020096);
  u16* xk = (u16*)(ws + 38797312);
  u16* xv = (u16*)(ws + 55574528);
  u16* qkvproj = (u16*)(ws + 72351744);
  u16* vt = xq;       // xq dead after fused QKV GEMM
  u16* attno = xk;    // xk dead after fused QKV GEMM

  k_init<<<dim3(35328), 256, 0, stream>>>(query, key_, value, Wq, Wk, Wv, Wo,
                                          xq, xk, xv, wq_bf, wk_bf, wv_bf, wo_bf, tab2);

  k_gemm_qkv<<<dim3(MROWS / 128, QKVS / 128), 256, 0, stream>>>(xq, xk, xv, wq_bf, wk_bf, wv_bf,
                                                                bq, bk, bv, tab2, qkvproj);

  k_transpose_v<<<dim3(MROWS / 64, KVDIM / 64), 256, 0, stream>>>(qkvproj + 2560, vt);

  k_attn<<<dim3(NSEQ / 128, QH, BATCH), 256, 0, stream>>>(qkvproj, qkvproj + 2048, vt, attno);

  k_gemm_bt<<<dim3(MROWS / 128, DIM_ / 128), 256, 0, stream>>>(attno, wo_bf, bo, (float*)d_out, MROWS, DIM_, DIM_);
}

// Round 15
// 228.971 us; speedup vs baseline: 7.0992x; 1.0184x over previous
//
#include <hip/hip_runtime.h>
#include <hip/hip_bf16.h>
#include <stdint.h>

typedef unsigned short u16;
typedef __bf16 v8bf __attribute__((ext_vector_type(8)));
typedef float f32x4 __attribute__((ext_vector_type(4)));

#define BATCH 2
#define NSEQ  2048
#define DIM_  2048
#define QH    16
#define KVH   4
#define HD    128
#define KVDIM 512
#define QKVS  3072
#define MROWS (BATCH*NSEQ)

__device__ __forceinline__ u16 f2bf(float f) {
  uint32_t u = __builtin_bit_cast(uint32_t, f);
  u += 0x7FFFu + ((u >> 16) & 1u);
  return (u16)(u >> 16);
}
__device__ __forceinline__ uint32_t cvt_pk_bf16(float lo, float hi) {
  uint32_t r;
  asm("v_cvt_pk_bf16_f32 %0, %1, %2" : "=v"(r) : "v"(lo), "v"(hi));
  return r;
}
__device__ __forceinline__ void gload_lds16(const void* g, void* l) {
  __builtin_amdgcn_global_load_lds((const __attribute__((address_space(1))) void*)g,
                                   (__attribute__((address_space(3))) void*)l, 16, 0, 0);
}

// ---------------- fused init: conv_x + conv_w + rope table ----------------
__global__ void k_init(const float* __restrict__ q, const float* __restrict__ k,
                       const float* __restrict__ v,
                       const float* __restrict__ wq, const float* __restrict__ wk,
                       const float* __restrict__ wv, const float* __restrict__ wo,
                       u16* __restrict__ xq, u16* __restrict__ xk, u16* __restrict__ xv,
                       u16* __restrict__ oq, u16* __restrict__ ok,
                       u16* __restrict__ ov, u16* __restrict__ oo,
                       float2* __restrict__ tab) {
  int bid = blockIdx.x;
  if (bid < 24576) {
    int i = (bid * 256 + threadIdx.x) * 4;
    int r = i >> 23;
    int e = i & ((1 << 23) - 1);
    const float* in = (r == 0) ? q : (r == 1 ? k : v);
    u16* out = (r == 0) ? xq : (r == 1 ? xk : xv);
    float4 vv = *(const float4*)(in + e);
    ushort4 o;
    o.x = f2bf(vv.x); o.y = f2bf(vv.y); o.z = f2bf(vv.z); o.w = f2bf(vv.w);
    *(ushort4*)(out + e) = o;
  } else if (bid < 34816) {
    int i = ((bid - 24576) * 256 + threadIdx.x) * 4;
    const float* in; u16* out; int e;
    if (i < 4194304)      { in = wq; out = oq; e = i; }
    else if (i < 5242880) { in = wk; out = ok; e = i - 4194304; }
    else if (i < 6291456) { in = wv; out = ov; e = i - 5242880; }
    else                  { in = wo; out = oo; e = i - 6291456; }
    float4 vv = *(const float4*)(in + e);
    ushort4 o;
    o.x = f2bf(vv.x); o.y = f2bf(vv.y); o.z = f2bf(vv.z); o.w = f2bf(vv.w);
    *(ushort4*)(out + e) = o;
  } else {
    int idx = (bid - 34816) * 256 + threadIdx.x;
    if (idx < NSEQ * 64) {
      int i = idx & 63;
      float inv = powf(10000.0f, -(float)i / 64.0f);
      float ang = (float)(idx >> 6) * inv;
      tab[idx] = make_float2(cosf(ang), sinf(ang));
    }
  }
}

// ------- V transpose, LDS-tiled 64x64 (coalesced both sides) -------
__global__ __launch_bounds__(256) void k_transpose_v(const u16* __restrict__ vp, u16* __restrict__ vt) {
  __shared__ u16 t[64][72];
  int bn = blockIdx.x, bd = blockIdx.y;
  int tid = threadIdx.x;
  int rrow = tid >> 3;
  int rcol = (tid & 7) * 8;
#pragma unroll
  for (int i = 0; i < 2; ++i) {
    int n = rrow + i * 32;
    ushort4 v0 = *(const ushort4*)(vp + (size_t)(bn * 64 + n) * QKVS + bd * 64 + rcol);
    ushort4 v1 = *(const ushort4*)(vp + (size_t)(bn * 64 + n) * QKVS + bd * 64 + rcol + 4);
    *(ushort4*)&t[n][rcol] = v0;
    *(ushort4*)&t[n][rcol + 4] = v1;
  }
  __syncthreads();
  int b = bn >> 5;
  int nbase = (bn & 31) * 64;
#pragma unroll
  for (int i = 0; i < 2; ++i) {
    int dl = rrow + i * 32;
    int dglob = bd * 64 + dl;
    int kvh = dglob >> 7, dd = dglob & 127;
    ushort4 o0, o1;
    o0.x = t[rcol + 0][dl]; o0.y = t[rcol + 1][dl];
    o0.z = t[rcol + 2][dl]; o0.w = t[rcol + 3][dl];
    o1.x = t[rcol + 4][dl]; o1.y = t[rcol + 5][dl];
    o1.z = t[rcol + 6][dl]; o1.w = t[rcol + 7][dl];
    u16* dst = vt + (((size_t)(b * KVH + kvh) * HD + dd) * NSEQ + nbase + rcol);
    *(ushort4*)dst = o0;
    *(ushort4*)(dst + 4) = o1;
  }
}

// ---- fused QKV GEMM (2-phase dbuf, bf16 A via global_load_lds): C(4096,3072) + RoPE ----
__global__ __launch_bounds__(256) void k_gemm_qkv(const u16* __restrict__ xq, const u16* __restrict__ xk,
                                                  const u16* __restrict__ xv,
                                                  const u16* __restrict__ wq, const u16* __restrict__ wk,
                                                  const u16* __restrict__ wv,
                                                  const float* __restrict__ bq, const float* __restrict__ bk,
                                                  const float* __restrict__ bv,
                                                  const float2* __restrict__ tab2, u16* __restrict__ C) {
  __shared__ __align__(16) u16 As[2][128 * 32];
  __shared__ __align__(16) u16 Bs[2][128 * 32];
  int tid = threadIdx.x;
  int l = tid & 63, w = tid >> 6;
  int lg = l >> 4, lr = l & 15;
  int wr = w >> 1, wc = w & 1;
  int bm = blockIdx.x, bn = blockIdx.y;

  const u16* A; const u16* B; const float* bias;
  if (bn < 16)      { A = xq; B = wq + (size_t)(bn * 128) * 2048;        bias = bq + bn * 128; }
  else if (bn < 20) { A = xk; B = wk + (size_t)((bn - 16) * 128) * 2048; bias = bk + (bn - 16) * 128; }
  else              { A = xv; B = wv + (size_t)((bn - 20) * 128) * 2048; bias = bv + (bn - 20) * 128; }

  int srow = tid >> 2;
  int scol = (tid & 3) * 16;

  const char* Ab = (const char*)A + ((size_t)(bm * 128 + srow) * 2048) * 2 + scol;
  const char* Bb = (const char*)B + ((size_t)srow * 2048) * 2 + scol;

#define STG(BUF, KT)                                                            \
  {                                                                             \
    size_t koff = (size_t)(KT) * 64;                                            \
    gload_lds16(Ab + koff, (char*)As[BUF] + srow * 64 + scol);                  \
    gload_lds16(Ab + koff + (size_t)64 * 2048 * 2,                              \
                (char*)As[BUF] + (srow + 64) * 64 + scol);                      \
    gload_lds16(Bb + koff, (char*)Bs[BUF] + srow * 64 + scol);                  \
    gload_lds16(Bb + koff + (size_t)64 * 2048 * 2,                              \
                (char*)Bs[BUF] + (srow + 64) * 64 + scol);                      \
  }

  f32x4 acc[4][4] = {};
  STG(0, 0);
  __syncthreads();
  for (int kt = 0; kt < 64; ++kt) {
    int cur = kt & 1;
    if (kt < 63) STG(cur ^ 1, kt + 1);
    const char* AsB = (const char*)As[cur];
    const char* BsB = (const char*)Bs[cur];
    v8bf af[4], bfr[4];
#pragma unroll
    for (int mi = 0; mi < 4; ++mi)
      af[mi] = *(const v8bf*)(AsB + (wr * 64 + mi * 16 + lr) * 64 + lg * 16);
#pragma unroll
    for (int ni = 0; ni < 4; ++ni)
      bfr[ni] = *(const v8bf*)(BsB + (wc * 64 + ni * 16 + lr) * 64 + lg * 16);
#pragma unroll
    for (int mi = 0; mi < 4; ++mi)
#pragma unroll
      for (int ni = 0; ni < 4; ++ni)
        acc[mi][ni] = __builtin_amdgcn_mfma_f32_16x16x32_bf16(af[mi], bfr[ni], acc[mi][ni], 0, 0, 0);
    __syncthreads();
  }
#undef STG

  bool rope = (bn < 20);
#pragma unroll
  for (int mi = 0; mi < 4; ++mi)
#pragma unroll
    for (int ni = 0; ni < 4; ++ni) {
      int grow0 = bm * 128 + wr * 64 + mi * 16 + lg * 4;
      int lcol = wc * 64 + ni * 16 + lr;
      int gcol = bn * 128 + lcol;
      float bsv = bias[lcol];
      if (rope) {
        int i2 = (gcol & 127) >> 1;
#pragma unroll
        for (int r = 0; r < 4; ++r) {
          float v = acc[mi][ni][r] + bsv;
          float pv = __shfl_xor(v, 1);
          int t = (grow0 + r) & (NSEQ - 1);
          float2 cs = tab2[t * 64 + i2];
          float y = (lr & 1) ? (pv * cs.y + v * cs.x) : (v * cs.x - pv * cs.y);
          C[(size_t)(grow0 + r) * QKVS + gcol] = f2bf(y);
        }
      } else {
#pragma unroll
        for (int r = 0; r < 4; ++r)
          C[(size_t)(grow0 + r) * QKVS + gcol] = f2bf(acc[mi][ni][r] + bsv);
      }
    }
}

// ---------------- bf16 GEMM (2-phase dbuf): fp32 out ----------------
__global__ __launch_bounds__(256) void k_gemm_bt(const u16* __restrict__ A, const u16* __restrict__ B,
                                                 const float* __restrict__ bias, float* __restrict__ C,
                                                 int M, int N, int K) {
  __shared__ __align__(16) u16 As[2][128 * 32];
  __shared__ __align__(16) u16 Bs[2][128 * 32];
  int tid = threadIdx.x;
  int l = tid & 63, w = tid >> 6;
  int lg = l >> 4, lr = l & 15;
  int wr = w >> 1, wc = w & 1;
  int bm = blockIdx.x, bn = blockIdx.y;

  int srow = tid >> 2;
  int scol = (tid & 3) * 16;

  const char* Ab = (const char*)A + ((size_t)(bm * 128 + srow) * K) * 2 + scol;
  const char* Bb = (const char*)B + ((size_t)(bn * 128 + srow) * K) * 2 + scol;

#define STG(BUF, KT)                                                            \
  {                                                                             \
    size_t koff = (size_t)(KT) * 64;                                            \
    gload_lds16(Ab + koff, (char*)As[BUF] + srow * 64 + scol);                  \
    gload_lds16(Ab + koff + (size_t)64 * K * 2,                                 \
                (char*)As[BUF] + (srow + 64) * 64 + scol);                      \
    gload_lds16(Bb + koff, (char*)Bs[BUF] + srow * 64 + scol);                  \
    gload_lds16(Bb + koff + (size_t)64 * K * 2,                                 \
                (char*)Bs[BUF] + (srow + 64) * 64 + scol);                      \
  }

  f32x4 acc[4][4] = {};
  int ksteps = K >> 5;
  STG(0, 0);
  __syncthreads();
  for (int kt = 0; kt < ksteps; ++kt) {
    int cur = kt & 1;
    if (kt + 1 < ksteps) STG(cur ^ 1, kt + 1);
    const char* AsB = (const char*)As[cur];
    const char* BsB = (const char*)Bs[cur];
    v8bf af[4], bfr[4];
#pragma unroll
    for (int mi = 0; mi < 4; ++mi)
      af[mi] = *(const v8bf*)(AsB + (wr * 64 + mi * 16 + lr) * 64 + lg * 16);
#pragma unroll
    for (int ni = 0; ni < 4; ++ni)
      bfr[ni] = *(const v8bf*)(BsB + (wc * 64 + ni * 16 + lr) * 64 + lg * 16);
#pragma unroll
    for (int mi = 0; mi < 4; ++mi)
#pragma unroll
      for (int ni = 0; ni < 4; ++ni)
        acc[mi][ni] = __builtin_amdgcn_mfma_f32_16x16x32_bf16(af[mi], bfr[ni], acc[mi][ni], 0, 0, 0);
    __syncthreads();
  }
#undef STG

#pragma unroll
  for (int mi = 0; mi < 4; ++mi)
#pragma unroll
    for (int ni = 0; ni < 4; ++ni) {
      int grow0 = bm * 128 + wr * 64 + mi * 16 + lg * 4;
      int gcol = bn * 128 + wc * 64 + ni * 16 + lr;
      float bsv = bias[gcol];
#pragma unroll
      for (int r = 0; r < 4; ++r)
        C[(size_t)(grow0 + r) * N + gcol] = acc[mi][ni][r] + bsv;
    }
}

// ---------------- flash attention v6: dbuf K/V LDS, 1 barrier/iter ----------------
__global__ __launch_bounds__(256, 2) void k_attn(const u16* __restrict__ q, const u16* __restrict__ k,
                                                 const u16* __restrict__ vt, u16* __restrict__ out) {
  __shared__ __align__(16) u16 Ks[2][64 * 128];   // rows=psi(kv), 256B rows, XOR-swizzled
  __shared__ __align__(16) u16 Vs[2][128 * 64];   // rows=d, 128B rows, XOR-swizzled

  int tid = threadIdx.x;
  int l = tid & 63, w = tid >> 6;
  int lg = l >> 4, lr = l & 15;
  int h = blockIdx.y, b = blockIdx.z;
  int kvh = h >> 2;
  const float SCL2 = 0.12752551286084109f;  // (1/sqrt(128)) * log2(e)
  const float THR2 = 11.541560327111708f;   // 8 * log2(e)

  const char* kbase = (const char*)k + ((size_t)(b * NSEQ) * QKVS + kvh * HD) * 2;
  const char* vbase = (const char*)vt + ((size_t)(b * KVH + kvh) * HD) * NSEQ * 2;

  int krow0 = tid >> 4;
  int kcol = (tid & 15) * 16;
  int vrow0 = tid >> 3;
  int vcol = (tid & 7) * 16;

  v8bf kr[4], vr[4];

#define LOADKV(KT)                                                                          \
  {                                                                                         \
    _Pragma("unroll") for (int i = 0; i < 4; ++i)                                           \
        kr[i] = *(const v8bf*)(kbase + (size_t)((KT) * 64 + krow0 + i * 16) * QKVS * 2 + kcol); \
    _Pragma("unroll") for (int i = 0; i < 4; ++i)                                           \
        vr[i] = *(const v8bf*)(vbase + (size_t)(vrow0 + i * 32) * NSEQ * 2 + (size_t)(KT) * 128 + vcol); \
  }
#define WRITEKV(BUF)                                                                        \
  {                                                                                         \
    char* KsB_ = (char*)Ks[BUF];                                                            \
    char* VsB_ = (char*)Vs[BUF];                                                            \
    _Pragma("unroll") for (int i = 0; i < 4; ++i) {                                         \
      int kvl = krow0 + i * 16;                                                             \
      int prow = (kvl & 32) + ((kvl & 4) << 2) + ((kvl & 24) >> 1) + (kvl & 3);             \
      *(v8bf*)(KsB_ + prow * 256 + (kcol ^ ((prow & 7) << 4))) = kr[i];                     \
    }                                                                                       \
    _Pragma("unroll") for (int i = 0; i < 4; ++i) {                                         \
      int row = vrow0 + i * 32;                                                             \
      *(v8bf*)(VsB_ + row * 128 + (vcol ^ ((row & 7) << 4))) = vr[i];                       \
    }                                                                                       \
  }

  for (int pass = 0; pass < 2; ++pass) {
    int qt = pass ? (31 - blockIdx.x) : blockIdx.x;
    int q0 = qt * 64 + w * 16;

    const char* qb = (const char*)q + ((size_t)(b * NSEQ + q0 + lr) * QKVS + h * HD) * 2;
    v8bf qf[4];
#pragma unroll
    for (int kk = 0; kk < 4; ++kk) qf[kk] = *(const v8bf*)(qb + kk * 64 + lg * 16);

    f32x4 od[8] = {};
    float m2 = -INFINITY, lsum = 0.f;
    int qrow = q0 + lr;

    int ktmax = qt;
    LOADKV(0);
    WRITEKV(0);
    __syncthreads();

    for (int kt = 0; kt <= ktmax; ++kt) {
      int cur = kt & 1;
      if (kt < ktmax) LOADKV(kt + 1);
      const char* KsB = (const char*)Ks[cur];
      const char* VsB = (const char*)Vs[cur];

      f32x4 st[4];
      __builtin_amdgcn_s_setprio(1);
#pragma unroll
      for (int nt = 0; nt < 4; ++nt) {
        f32x4 a = {};
#pragma unroll
        for (int kk = 0; kk < 4; ++kk) {
          int krow = nt * 16 + lr;
          v8bf kf = *(const v8bf*)(KsB + krow * 256 + ((kk * 64 + lg * 16) ^ ((krow & 7) << 4)));
          a = __builtin_amdgcn_mfma_f32_16x16x32_bf16(kf, qf[kk], a, 0, 0, 0);
        }
        st[nt] = a;
      }
      __builtin_amdgcn_s_setprio(0);

      if (kt == ktmax) {
#pragma unroll
        for (int nt = 0; nt < 4; ++nt)
#pragma unroll
          for (int r = 0; r < 4; ++r) {
            int kv = kt * 64 + (nt >> 1) * 32 + lg * 8 + ((nt & 1) << 2) + r;
            if (kv > qrow) st[nt][r] = -1e30f;
          }
      }

      float mx = -1e30f;
#pragma unroll
      for (int nt = 0; nt < 4; ++nt)
#pragma unroll
        for (int r = 0; r < 4; ++r) mx = fmaxf(mx, st[nt][r]);
      mx = fmaxf(mx, __shfl_xor(mx, 16));
      mx = fmaxf(mx, __shfl_xor(mx, 32));
      float mx2 = mx * SCL2;

      if (!__all(mx2 - m2 <= THR2)) {
        float nm2 = fmaxf(m2, mx2);
        float corrf = exp2f(m2 - nm2);
        m2 = nm2;
        lsum *= corrf;
#pragma unroll
        for (int r = 0; r < 4; ++r) {
          float cb = __shfl(corrf, lg * 4 + r);
#pragma unroll
          for (int dt = 0; dt < 8; ++dt) od[dt][r] *= cb;
        }
      }

      float rs = 0.f;
#pragma unroll
      for (int nt = 0; nt < 4; ++nt)
#pragma unroll
        for (int r = 0; r < 4; ++r) {
          float pv = exp2f(fmaf(st[nt][r], SCL2, -m2));
          st[nt][r] = pv;
          rs += pv;
        }
      rs += __shfl_xor(rs, 16);
      rs += __shfl_xor(rs, 32);
      lsum += rs;

      uint32_t pk[4][2];
#pragma unroll
      for (int nt = 0; nt < 4; ++nt)
#pragma unroll
        for (int s = 0; s < 2; ++s)
          pk[nt][s] = cvt_pk_bf16(st[nt][2 * s], st[nt][2 * s + 1]);

      __builtin_amdgcn_s_setprio(1);
#pragma unroll
      for (int kc = 0; kc < 2; ++kc) {
        union { uint32_t u[4]; v8bf v; } pfu;
        pfu.u[0] = pk[2 * kc][0];
        pfu.u[1] = pk[2 * kc][1];
        pfu.u[2] = pk[2 * kc + 1][0];
        pfu.u[3] = pk[2 * kc + 1][1];
#pragma unroll
        for (int dt = 0; dt < 8; ++dt) {
          int vrow = dt * 16 + lr;
          v8bf vf = *(const v8bf*)(VsB + vrow * 128 + ((kc * 64 + lg * 16) ^ ((vrow & 7) << 4)));
          od[dt] = __builtin_amdgcn_mfma_f32_16x16x32_bf16(pfu.v, vf, od[dt], 0, 0, 0);
        }
      }
      __builtin_amdgcn_s_setprio(0);

      if (kt < ktmax) WRITEKV(cur ^ 1);
      __syncthreads();
    }

#pragma unroll
    for (int r = 0; r < 4; ++r) {
      float ls = __shfl(lsum, lg * 4 + r);
      float inv = 1.0f / ls;
      int qr = q0 + lg * 4 + r;
      char* ob = (char*)out + ((size_t)(b * NSEQ + qr) * DIM_ + h * HD) * 2;
#pragma unroll
      for (int dt = 0; dt < 8; ++dt)
        *(u16*)(ob + (dt * 16 + lr) * 2) = f2bf(od[dt][r] * inv);
    }
  }
#undef LOADKV
#undef WRITEKV
}

// ---------------- launch ----------------
extern "C" void kernel_launch(void* const* d_in, const int* in_sizes, int n_in,
                              void* d_out, int out_size, void* d_ws, size_t ws_size,
                              hipStream_t stream) {
  const float* query = (const float*)d_in[0];
  const float* key_ = (const float*)d_in[1];
  const float* value = (const float*)d_in[2];
  const float* Wq = (const float*)d_in[3];
  const float* bq = (const float*)d_in[4];
  const float* Wk = (const float*)d_in[5];
  const float* bk = (const float*)d_in[6];
  const float* Wv = (const float*)d_in[7];
  const float* bv = (const float*)d_in[8];
  const float* Wo = (const float*)d_in[9];
  const float* bo = (const float*)d_in[10];

  char* ws = (char*)d_ws;
  u16* wq_bf = (u16*)(ws + 0);
  u16* wk_bf = (u16*)(ws + 8388608);
  u16* wv_bf = (u16*)(ws + 10485760);
  u16* wo_bf = (u16*)(ws + 12582912);
  float2* tab2 = (float2*)(ws + 20971520);
  u16* xq = (u16*)(ws + 22020096);
  u16* xk = (u16*)(ws + 38797312);
  u16* xv = (u16*)(ws + 55574528);
  u16* qkvproj = (u16*)(ws + 72351744);
  u16* vt = xq;       // xq dead after fused QKV GEMM
  u16* attno = xk;    // xk dead after fused QKV GEMM

  k_init<<<dim3(35328), 256, 0, stream>>>(query, key_, value, Wq, Wk, Wv, Wo,
                                          xq, xk, xv, wq_bf, wk_bf, wv_bf, wo_bf, tab2);

  k_gemm_qkv<<<dim3(MROWS / 128, QKVS / 128), 256, 0, stream>>>(xq, xk, xv, wq_bf, wk_bf, wv_bf,
                                                                bq, bk, bv, tab2, qkvproj);

  k_transpose_v<<<dim3(MROWS / 64, KVDIM / 64), 256, 0, stream>>>(qkvproj + 2560, vt);

  k_attn<<<dim3(NSEQ / 128, QH, BATCH), 256, 0, stream>>>(qkvproj, qkvproj + 2048, vt, attno);

  k_gemm_bt<<<dim3(MROWS / 128, DIM_ / 128), 256, 0, stream>>>(attno, wo_bf, bo, (float*)d_out, MROWS, DIM_, DIM_);
}